// Round 5
// baseline (2107.048 us; speedup 1.0000x reference)
//
#include <hip/hip_runtime.h>

#define NN 100000
#define FIN 1433
#define KSTEPS 45        // ceil(1433/32)
#define NPAD 100352      // 98 * 1024 (scan padding)
#define PSB 98           // scan phase-1 blocks

typedef __attribute__((ext_vector_type(8))) short s16x8;
typedef __attribute__((ext_vector_type(4))) float f32x4;

__device__ __forceinline__ short f2bf(float f){
  unsigned u = __float_as_uint(f);
  unsigned r = (u + 0x7fffu + ((u >> 16) & 1u)) >> 16;
  return (short)r;
}
__device__ __forceinline__ float bflo(unsigned u){ return __uint_as_float(u << 16); }
__device__ __forceinline__ float bfhi(unsigned u){ return __uint_as_float(u & 0xffff0000u); }

__device__ __forceinline__ f32x4 mfma16(s16x8 a, s16x8 b, f32x4 c){
  return __builtin_amdgcn_mfma_f32_16x16x32_bf16(a, b, c, 0, 0, 0);
}

// ---------------- CSR build ----------------
__global__ void init_k(int* __restrict__ counts, int n){
  int i = blockIdx.x * 256 + threadIdx.x;
  if (i < NPAD) counts[i] = (i < n) ? 1 : 0;   // 1 = reserved self-loop slot
}

__global__ void hist_k(const int* __restrict__ dsts, int* __restrict__ counts, int E){
  int i = blockIdx.x * 256 + threadIdx.x;
  if (i < E) atomicAdd(&counts[dsts[i]], 1);
}

// phase 1: per-block (1024 elems) int4 prefix + block sums
__global__ void psum_k(const int* __restrict__ counts, int* __restrict__ pre,
                       int* __restrict__ bsum){
  __shared__ int ls[256];
  int blk = blockIdx.x, t = threadIdx.x;
  int4 v = ((const int4*)(counts + blk * 1024))[t];
  int s = v.x + v.y + v.z + v.w;
  ls[t] = s;
  __syncthreads();
  for (int off = 1; off < 256; off <<= 1){
    int u = (t >= off) ? ls[t - off] : 0;
    __syncthreads();
    ls[t] += u;
    __syncthreads();
  }
  int excl = ls[t] - s;
  int4 o;
  o.x = excl; o.y = o.x + v.x; o.z = o.y + v.y; o.w = o.z + v.z;
  ((int4*)(pre + blk * 1024))[t] = o;
  if (t == 255) bsum[blk] = ls[255];
}

// phase 2: scan the 98 block sums
__global__ void scan2_k(const int* __restrict__ bsum, int* __restrict__ boff){
  __shared__ int ls[128];
  int t = threadIdx.x;
  int v = (t < PSB) ? bsum[t] : 0;
  ls[t] = v;
  __syncthreads();
  for (int off = 1; off < 128; off <<= 1){
    int u = (t >= off) ? ls[t - off] : 0;
    __syncthreads();
    ls[t] += u;
    __syncthreads();
  }
  if (t < PSB) boff[t] = ls[t] - v;
}

// phase 3: add block offsets -> rowp, cursor; fused self-loop scatter
__global__ void addoff_k(const int* __restrict__ pre, const int* __restrict__ boff,
                         int* __restrict__ rowp, int* __restrict__ cursor,
                         int* __restrict__ colv, int n){
  int blk = blockIdx.x, t = threadIdx.x;
  int off = boff[blk];
  int4 p = ((const int4*)(pre + blk * 1024))[t];
  p.x += off; p.y += off; p.z += off; p.w += off;
  ((int4*)(rowp + blk * 1024))[t] = p;
  int4 c = p; c.x += 1; c.y += 1; c.z += 1; c.w += 1;
  ((int4*)(cursor + blk * 1024))[t] = c;   // self-loop slot consumed
  int base = blk * 1024 + t * 4;
  if (base + 0 < n) colv[p.x] = base + 0;
  if (base + 1 < n) colv[p.y] = base + 1;
  if (base + 2 < n) colv[p.z] = base + 2;
  if (base + 3 < n) colv[p.w] = base + 3;
}

__global__ void scatter_k(const int* __restrict__ srcs, const int* __restrict__ dsts,
                          int* __restrict__ cursor, int* __restrict__ colv, int E){
  int i = blockIdx.x * 256 + threadIdx.x;
  if (i < E){
    int d = dsts[i];
    int p = atomicAdd(&cursor[d], 1);
    colv[p] = srcs[i];
  }
}

// ---------------- W1 fragment prepack ----------------
__global__ void w1pack_k(const float* __restrict__ W1, short* __restrict__ pack){
  int ks = blockIdx.x >> 2, nf = blockIdx.x & 3, l = threadIdx.x;
  int col = nf * 16 + (l & 15);
  s16x8 v;
  #pragma unroll
  for (int j = 0; j < 8; j++){
    int k = ks * 32 + ((l >> 4) * 8) + j;
    float f = (k < FIN) ? W1[k * 64 + col] : 0.0f;
    v[j] = f2bf(f);
  }
  *(s16x8*)&pack[((size_t)(ks * 4 + nf) * 64 + l) * 8] = v;
}

// ---------------- GEMM1: h1b = bf16(x @ W1)  [N,64] ----------------
// INSTRUMENTED: reps loops the whole body (idempotent) for rocprof visibility.
__global__ __launch_bounds__(256) void gemm1_k(const float* __restrict__ x,
                                               const short* __restrict__ w1p,
                                               unsigned short* __restrict__ h1b,
                                               int n, int reps){
  int tid = threadIdx.x;
  int wid = tid >> 6, lane = tid & 63;
  int row0 = blockIdx.x * 128;
  int g = lane >> 4;

  for (int rep = 0; rep < reps; rep++){
    f32x4 acc[2][4] = {};
    int r0 = min(row0 + wid * 32 +      (lane & 15), n - 1);
    int r1 = min(row0 + wid * 32 + 16 + (lane & 15), n - 1);
    const float* pa0 = x + (size_t)r0 * FIN + g * 8;
    const float* pa1 = x + (size_t)r1 * FIN + g * 8;
    const s16x8* pb  = ((const s16x8*)w1p) + lane;

    float c0[8], c1[8], n0[8], n1[8];
    #pragma unroll
    for (int j = 0; j < 8; j++){
      c0[j] = pa0[j];
      c1[j] = pa1[j];
    }

    #pragma unroll 2
    for (int ks = 0; ks < 43; ks++){
      const float* q0 = pa0 + (ks + 1) * 32;
      const float* q1 = pa1 + (ks + 1) * 32;
      #pragma unroll
      for (int j = 0; j < 8; j++){
        n0[j] = q0[j];
        n1[j] = q1[j];
      }
      s16x8 b0 = pb[(ks * 4 + 0) * 64];
      s16x8 b1 = pb[(ks * 4 + 1) * 64];
      s16x8 b2 = pb[(ks * 4 + 2) * 64];
      s16x8 b3 = pb[(ks * 4 + 3) * 64];
      s16x8 a0, a1;
      #pragma unroll
      for (int j = 0; j < 8; j++){ a0[j] = f2bf(c0[j]); a1[j] = f2bf(c1[j]); }
      acc[0][0] = mfma16(a0, b0, acc[0][0]);
      acc[0][1] = mfma16(a0, b1, acc[0][1]);
      acc[0][2] = mfma16(a0, b2, acc[0][2]);
      acc[0][3] = mfma16(a0, b3, acc[0][3]);
      acc[1][0] = mfma16(a1, b0, acc[1][0]);
      acc[1][1] = mfma16(a1, b1, acc[1][1]);
      acc[1][2] = mfma16(a1, b2, acc[1][2]);
      acc[1][3] = mfma16(a1, b3, acc[1][3]);
      #pragma unroll
      for (int j = 0; j < 8; j++){ c0[j] = n0[j]; c1[j] = n1[j]; }
    }

    { // ks=43: prefetch masked tail (k0=1408, valid k offsets: g*8+j < 25)
      const float* q0 = pa0 + 44 * 32;
      const float* q1 = pa1 + 44 * 32;
      #pragma unroll
      for (int j = 0; j < 8; j++){
        bool ok = (g * 8 + j) < 25;
        int jj = ok ? j : 0;
        float v0 = q0[jj];
        float v1 = q1[jj];
        n0[j] = ok ? v0 : 0.0f;
        n1[j] = ok ? v1 : 0.0f;
      }
      const int ks = 43;
      s16x8 b0 = pb[(ks * 4 + 0) * 64];
      s16x8 b1 = pb[(ks * 4 + 1) * 64];
      s16x8 b2 = pb[(ks * 4 + 2) * 64];
      s16x8 b3 = pb[(ks * 4 + 3) * 64];
      s16x8 a0, a1;
      #pragma unroll
      for (int j = 0; j < 8; j++){ a0[j] = f2bf(c0[j]); a1[j] = f2bf(c1[j]); }
      acc[0][0] = mfma16(a0, b0, acc[0][0]);
      acc[0][1] = mfma16(a0, b1, acc[0][1]);
      acc[0][2] = mfma16(a0, b2, acc[0][2]);
      acc[0][3] = mfma16(a0, b3, acc[0][3]);
      acc[1][0] = mfma16(a1, b0, acc[1][0]);
      acc[1][1] = mfma16(a1, b1, acc[1][1]);
      acc[1][2] = mfma16(a1, b2, acc[1][2]);
      acc[1][3] = mfma16(a1, b3, acc[1][3]);
      #pragma unroll
      for (int j = 0; j < 8; j++){ c0[j] = n0[j]; c1[j] = n1[j]; }
    }
    { // ks=44 tail compute
      const int ks = 44;
      s16x8 b0 = pb[(ks * 4 + 0) * 64];
      s16x8 b1 = pb[(ks * 4 + 1) * 64];
      s16x8 b2 = pb[(ks * 4 + 2) * 64];
      s16x8 b3 = pb[(ks * 4 + 3) * 64];
      s16x8 a0, a1;
      #pragma unroll
      for (int j = 0; j < 8; j++){ a0[j] = f2bf(c0[j]); a1[j] = f2bf(c1[j]); }
      acc[0][0] = mfma16(a0, b0, acc[0][0]);
      acc[0][1] = mfma16(a0, b1, acc[0][1]);
      acc[0][2] = mfma16(a0, b2, acc[0][2]);
      acc[0][3] = mfma16(a0, b3, acc[0][3]);
      acc[1][0] = mfma16(a1, b0, acc[1][0]);
      acc[1][1] = mfma16(a1, b1, acc[1][1]);
      acc[1][2] = mfma16(a1, b2, acc[1][2]);
      acc[1][3] = mfma16(a1, b3, acc[1][3]);
    }

    // epilogue: pack col pairs to bf16 dwords; even lanes store.
    #pragma unroll
    for (int mf = 0; mf < 2; mf++){
      #pragma unroll
      for (int r4 = 0; r4 < 4; r4++){
        int m = row0 + wid * 32 + mf * 16 + (lane >> 4) * 4 + r4;
        if (m < n){
          #pragma unroll
          for (int nf = 0; nf < 4; nf++){
            float v = acc[mf][nf][r4];
            float pv = __shfl_xor(v, 1);
            if ((lane & 1) == 0){
              unsigned pk = (unsigned)(unsigned short)f2bf(v) |
                            ((unsigned)(unsigned short)f2bf(pv) << 16);
              *(unsigned*)&h1b[(size_t)m * 64 + nf * 16 + (lane & 15)] = pk;
            }
          }
        }
      }
    }
  }
}

// ---------------- per-(node,head) attention logits, layer 1 ----------------
__global__ void alphas1_k(const unsigned short* __restrict__ h1b,
                          const float* __restrict__ a1s, const float* __restrict__ a1d,
                          float* __restrict__ as1, float* __restrict__ ad1, int n8){
  int idx = blockIdx.x * 256 + threadIdx.x;
  if (idx >= n8) return;
  int h = idx & 7;
  uint4 u = ((const uint4*)h1b)[idx];
  float f[8] = { bflo(u.x), bfhi(u.x), bflo(u.y), bfhi(u.y),
                 bflo(u.z), bfhi(u.z), bflo(u.w), bfhi(u.w) };
  float s = 0.0f, d = 0.0f;
  #pragma unroll
  for (int j = 0; j < 8; j++){
    s += f[j] * a1s[h * 8 + j];
    d += f[j] * a1d[h * 8 + j];
  }
  as1[idx] = s; ad1[idx] = d;
}

// ---------------- layer-1 aggregation: wave/node, 4 edges in flight --------
// INSTRUMENTED: reps loops the body (idempotent).
// lane sl=l&15 owns features 4sl..4sl+3 (one 8B read); qw=l>>4 owns edge
// stream i = beg+qw step 4. Self-loop is in the CSR.
__global__ void agg1_k(const int* __restrict__ rowp, const int* __restrict__ colv,
                       const unsigned short* __restrict__ h1b,
                       const float* __restrict__ as1, const float* __restrict__ ad1,
                       const float* __restrict__ b1, float* __restrict__ h2in,
                       int n, int reps){
  int node = blockIdx.x * 4 + (threadIdx.x >> 6);
  if (node >= n) return;
  int l = threadIdx.x & 63, sl = l & 15, qw = l >> 4;
  int h = sl >> 1;                       // head of features 4sl..4sl+3
  for (int rep = 0; rep < reps; rep++){
    float adn = ad1[node * 8 + h];
    float ax = 0.0f, ay = 0.0f, az = 0.0f, aw = 0.0f, sw = 0.0f;
    int beg = rowp[node], end = rowp[node + 1];
    for (int i = beg + qw; i < end; i += 4){
      int s0 = colv[i];
      float e0 = as1[s0 * 8 + h] + adn;
      uint2 u0 = *(const uint2*)(h1b + (size_t)s0 * 64 + 4 * sl);
      e0 = e0 > 0.0f ? e0 : 0.2f * e0;
      float w0 = __expf(e0);
      ax += w0 * bflo(u0.x); ay += w0 * bfhi(u0.x);
      az += w0 * bflo(u0.y); aw += w0 * bfhi(u0.y);
      sw += w0;
    }
    sw += __shfl_xor(sw, 16); sw += __shfl_xor(sw, 32);
    ax += __shfl_xor(ax, 16); ax += __shfl_xor(ax, 32);
    ay += __shfl_xor(ay, 16); ay += __shfl_xor(ay, 32);
    az += __shfl_xor(az, 16); az += __shfl_xor(az, 32);
    aw += __shfl_xor(aw, 16); aw += __shfl_xor(aw, 32);
    if (qw == 0){
      float inv = 1.0f / (sw + 1e-16f);
      float4 bv = *(const float4*)&b1[4 * sl];
      float ox = ax * inv + bv.x;
      float oy = ay * inv + bv.y;
      float oz = az * inv + bv.z;
      float ow = aw * inv + bv.w;
      float4 o = make_float4(ox > 0.0f ? ox : 0.0f, oy > 0.0f ? oy : 0.0f,
                             oz > 0.0f ? oz : 0.0f, ow > 0.0f ? ow : 0.0f);
      *(float4*)&h2in[(size_t)node * 64 + 4 * sl] = o;
    }
  }
}

// ---------------- layer-2 projection + logits ----------------
__global__ void gemm2_k(const float* __restrict__ h2in, const float* __restrict__ W2,
                        const float* __restrict__ a2s, const float* __restrict__ a2d,
                        float* __restrict__ h2, float* __restrict__ vs2,
                        float* __restrict__ vd2, int n){
  __shared__ float w2s[64 * 7];
  __shared__ float a2ss[7], a2ds[7];
  int t = threadIdx.x;
  for (int i = t; i < 448; i += 256) w2s[i] = W2[i];
  if (t < 7){ a2ss[t] = a2s[t]; a2ds[t] = a2d[t]; }
  __syncthreads();
  int node = blockIdx.x * 256 + t;
  if (node >= n) return;
  float acc[7] = {0,0,0,0,0,0,0};
  const float4* hr4 = (const float4*)(h2in + (size_t)node * 64);
  #pragma unroll
  for (int k4 = 0; k4 < 16; k4++){
    float4 v = hr4[k4];
    #pragma unroll
    for (int c = 0; c < 7; c++){
      acc[c] += v.x * w2s[(4 * k4 + 0) * 7 + c];
      acc[c] += v.y * w2s[(4 * k4 + 1) * 7 + c];
      acc[c] += v.z * w2s[(4 * k4 + 2) * 7 + c];
      acc[c] += v.w * w2s[(4 * k4 + 3) * 7 + c];
    }
  }
  float s = 0.0f, d = 0.0f;
  #pragma unroll
  for (int c = 0; c < 7; c++){
    s += acc[c] * a2ss[c];
    d += acc[c] * a2ds[c];
    h2[(size_t)node * 7 + c] = acc[c];
  }
  vs2[node] = s; vd2[node] = d;
}

// ---------------- layer-2 aggregation + log_softmax (8 lanes/node) ----------
__global__ void agg2_k(const int* __restrict__ rowp, const int* __restrict__ colv,
                       const float* __restrict__ h2, const float* __restrict__ vs2,
                       const float* __restrict__ vd2, const float* __restrict__ b2,
                       float* __restrict__ out, int n){
  int t = threadIdx.x;
  int node = blockIdx.x * 32 + (t >> 3);
  int c = t & 7;
  if (node >= n) return;
  bool cls = c < 7;
  float adn = vd2[node];
  float acc = 0.0f, sw = 0.0f;
  int beg = rowp[node], end = rowp[node + 1];   // includes self-loop
  int i = beg;
  for (; i + 1 < end; i += 2){
    int s0 = colv[i], s1 = colv[i + 1];
    float e0 = vs2[s0] + adn;
    float e1 = vs2[s1] + adn;
    float v0 = cls ? h2[(size_t)s0 * 7 + c] : 0.0f;
    float v1 = cls ? h2[(size_t)s1 * 7 + c] : 0.0f;
    e0 = e0 > 0.0f ? e0 : 0.2f * e0;
    e1 = e1 > 0.0f ? e1 : 0.2f * e1;
    float w0 = __expf(e0), w1 = __expf(e1);
    acc += w0 * v0 + w1 * v1;
    sw += w0 + w1;
  }
  for (; i < end; i++){
    int s0 = colv[i];
    float e0 = vs2[s0] + adn;
    e0 = e0 > 0.0f ? e0 : 0.2f * e0;
    float w0 = __expf(e0);
    acc += w0 * (cls ? h2[(size_t)s0 * 7 + c] : 0.0f);
    sw += w0;
  }
  float inv = 1.0f / (sw + 1e-16f);
  float o = cls ? acc * inv + b2[c] : -1e30f;
  float m = o;
  m = fmaxf(m, __shfl_xor(m, 1, 8));
  m = fmaxf(m, __shfl_xor(m, 2, 8));
  m = fmaxf(m, __shfl_xor(m, 4, 8));
  float ex = cls ? __expf(o - m) : 0.0f;
  float s8 = ex;
  s8 += __shfl_xor(s8, 1, 8);
  s8 += __shfl_xor(s8, 2, 8);
  s8 += __shfl_xor(s8, 4, 8);
  if (cls) out[(size_t)node * 7 + c] = o - m - __logf(s8);
}

extern "C" void kernel_launch(void* const* d_in, const int* in_sizes, int n_in,
                              void* d_out, int out_size, void* d_ws, size_t ws_size,
                              hipStream_t stream){
  const float* x   = (const float*)d_in[0];
  const int*   ei  = (const int*)d_in[1];
  const float* W1  = (const float*)d_in[2];
  const float* a1s = (const float*)d_in[3];
  const float* a1d = (const float*)d_in[4];
  const float* b1  = (const float*)d_in[5];
  const float* W2  = (const float*)d_in[6];
  const float* a2s = (const float*)d_in[7];
  const float* a2d = (const float*)d_in[8];
  const float* b2  = (const float*)d_in[9];
  int E = in_sizes[1] / 2;
  const int* srcs = ei;
  const int* dsts = ei + E;
  int n = in_sizes[0] / FIN;

  char* ws = (char*)d_ws;
  size_t off = 0;
  auto alloc = [&](size_t bytes)->void*{
    void* p = ws + off; off += (bytes + 255) & ~(size_t)255; return p;
  };
  unsigned short* h1b = (unsigned short*)alloc((size_t)n * 64 * 2);
  float* h2in = (float*)alloc((size_t)n * 64 * 4);
  float* as1  = (float*)alloc((size_t)n * 8 * 4);
  float* ad1  = (float*)alloc((size_t)n * 8 * 4);
  float* h2   = (float*)alloc((size_t)n * 7 * 4);
  float* vs2  = (float*)alloc((size_t)n * 4);
  float* vd2  = (float*)alloc((size_t)n * 4);
  int* counts = (int*)alloc((size_t)NPAD * 4);
  int* pre    = (int*)alloc((size_t)NPAD * 4);
  int* rowp   = (int*)alloc((size_t)NPAD * 4);
  int* cursor = (int*)alloc((size_t)NPAD * 4);
  int* bsum   = (int*)alloc((size_t)PSB * 4);
  int* boff   = (int*)alloc((size_t)PSB * 4);
  int* colv   = (int*)alloc((size_t)(E + n + 256) * 4);
  short* w1p  = (short*)alloc((size_t)KSTEPS * 4 * 64 * 8 * 2);
  (void)ws_size; (void)n_in; (void)out_size;

  init_k<<<(NPAD + 255) / 256, 256, 0, stream>>>(counts, n);
  hist_k<<<(E + 255) / 256, 256, 0, stream>>>(dsts, counts, E);
  psum_k<<<PSB, 256, 0, stream>>>(counts, pre, bsum);
  scan2_k<<<1, 128, 0, stream>>>(bsum, boff);
  addoff_k<<<PSB, 256, 0, stream>>>(pre, boff, rowp, cursor, colv, n);
  scatter_k<<<(E + 255) / 256, 256, 0, stream>>>(srcs, dsts, cursor, colv, E);
  w1pack_k<<<KSTEPS * 4, 64, 0, stream>>>(W1, w1p);
  gemm1_k<<<(n + 127) / 128, 256, 0, stream>>>(x, w1p, h1b, n, 4);      // x4 diag
  alphas1_k<<<(n * 8 + 255) / 256, 256, 0, stream>>>(h1b, a1s, a1d, as1, ad1, n * 8);
  agg1_k<<<(n + 3) / 4, 256, 0, stream>>>(rowp, colv, h1b, as1, ad1, b1, h2in, n, 8); // x8 diag
  gemm2_k<<<(n + 255) / 256, 256, 0, stream>>>(h2in, W2, a2s, a2d, h2, vs2, vd2, n);
  agg2_k<<<(n + 31) / 32, 256, 0, stream>>>(rowp, colv, h2, vs2, vd2, b2, (float*)d_out, n);
}